// Round 9
// baseline (250.758 us; speedup 1.0000x reference)
//
#include <hip/hip_runtime.h>
#include <math.h>

#define TOK 25

typedef __attribute__((ext_vector_type(8))) short short8_t;   // 8 bf16 (MFMA frag)
typedef __attribute__((ext_vector_type(4))) float f32x4_t;    // MFMA acc
typedef __attribute__((ext_vector_type(8))) float floatx8;
typedef __attribute__((ext_vector_type(4))) float floatx4;
typedef __attribute__((ext_vector_type(8))) __bf16 bf16x8_t;
typedef __attribute__((ext_vector_type(4))) __bf16 bf16x4_t;

// f32x8 -> bf16x8 via v_cvt_pk_bf16_f32 (compiler-lowered), as MFMA short8 frag
__device__ __forceinline__ short8_t cvt8(floatx8 f) {
  return __builtin_bit_cast(short8_t, __builtin_convertvector(f, bf16x8_t));
}
__device__ __forceinline__ uint2 cvt4pack(float4 v) {
  floatx4 f = {v.x, v.y, v.z, v.w};
  return __builtin_bit_cast(uint2, __builtin_convertvector(f, bf16x4_t));
}
__device__ __forceinline__ unsigned short bf1(float f) {
  return __builtin_bit_cast(unsigned short, (__bf16)f);
}

// ---------------- MFMA GEMM: part[s][25][N] = A[25][k-chunk] * W-chunk
// Block: 4 waves, 256 cols; wave owns 64 cols (4 groups of 16).
// A staged in LDS as bf16. One-step register double-buffer on the W stream.
// WT=0: W[K][N].  WT=1: W[N][K].
// LN=1: A-source is f32 T + per-row stats; apply LayerNorm during staging.
template <int KC, int WT, int LN>
__global__ __launch_bounds__(256) void k_mfma(
    const void* __restrict__ Av, const float* __restrict__ W,
    const float* __restrict__ stats, const float* __restrict__ lng,
    const float* __restrict__ lnb, float* __restrict__ part, int K, int N) {
  constexpr int LDA = KC + 8;  // bf16 elems/row; +16B pad
  __shared__ __align__(16) unsigned short As[TOK * LDA];
  __shared__ float ms[TOK], rs[TOK];
  const int tid = threadIdx.x;
  const int lane = tid & 63;
  const int lm = lane & 15;   // A row / B col within 16
  const int lg = lane >> 4;   // k-group (8 elems)
  const int wv = tid >> 6;
  const int s = blockIdx.y;
  const int k0 = s * KC;
  const int c0 = blockIdx.x * 256 + wv * 64;  // wave's first col
  // ---- LN stats -> LDS
  if (LN) {
    if (tid < TOK) {
      float s1 = stats[tid * 2], s2 = stats[tid * 2 + 1];
      float mean = s1 * (1.f / 4096.f);
      float var = s2 * (1.f / 4096.f) - mean * mean;
      ms[tid] = mean;
      rs[tid] = rsqrtf(var + 1e-5f);
    }
    __syncthreads();
  }
  // ---- stage A tile: 25 x KC bf16
  for (int i = tid; i < TOK * (KC / 8); i += 256) {
    int r = i / (KC / 8);
    int o = i - r * (KC / 8);
    if (LN) {
      const float* tp = (const float*)Av + (long)r * K + k0 + o * 8;
      float4 lo = *reinterpret_cast<const float4*>(tp);
      float4 hi = *reinterpret_cast<const float4*>(tp + 4);
      const float* gp = lng + k0 + o * 8;
      const float* bp = lnb + k0 + o * 8;
      float4 g0 = *reinterpret_cast<const float4*>(gp);
      float4 g1 = *reinterpret_cast<const float4*>(gp + 4);
      float4 b0 = *reinterpret_cast<const float4*>(bp);
      float4 b1 = *reinterpret_cast<const float4*>(bp + 4);
      float m = ms[r], rr = rs[r];
      floatx8 f = {(lo.x - m) * rr * g0.x + b0.x, (lo.y - m) * rr * g0.y + b0.y,
                   (lo.z - m) * rr * g0.z + b0.z, (lo.w - m) * rr * g0.w + b0.w,
                   (hi.x - m) * rr * g1.x + b1.x, (hi.y - m) * rr * g1.y + b1.y,
                   (hi.z - m) * rr * g1.z + b1.z, (hi.w - m) * rr * g1.w + b1.w};
      *reinterpret_cast<short8_t*>(&As[r * LDA + o * 8]) = cvt8(f);
    } else {
      uint4 v = *reinterpret_cast<const uint4*>((const unsigned short*)Av +
                                                (long)r * K + k0 + o * 8);
      *reinterpret_cast<uint4*>(&As[r * LDA + o * 8]) = v;
    }
  }
  __syncthreads();
  const int r1 = 16 + lm;
  const int r1c = (r1 < TOK) ? r1 : 0;  // clamped; tile-1 rows >=25 dropped
  f32x4_t acc[4][2];
#pragma unroll
  for (int g = 0; g < 4; ++g) {
    acc[g][0] = (f32x4_t){0.f, 0.f, 0.f, 0.f};
    acc[g][1] = (f32x4_t){0.f, 0.f, 0.f, 0.f};
  }
  auto loadW = [&](int ks, floatx8(&dst)[4]) {
    const int kb = k0 + ks + lg * 8;
    if (WT == 0) {
      const float* bp = W + (long)kb * N + c0 + lm;
#pragma unroll
      for (int j = 0; j < 8; ++j) {
        const float* bj = bp + (long)j * N;
#pragma unroll
        for (int g = 0; g < 4; ++g) dst[g][j] = bj[g * 16];
      }
    } else {
#pragma unroll
      for (int g = 0; g < 4; ++g) {
        const float* bp = W + (long)(c0 + g * 16 + lm) * K + kb;
        float4 b0 = *reinterpret_cast<const float4*>(bp);
        float4 b1 = *reinterpret_cast<const float4*>(bp + 4);
        dst[g] = (floatx8){b0.x, b0.y, b0.z, b0.w, b1.x, b1.y, b1.z, b1.w};
      }
    }
  };
  floatx8 wcur[4], wnxt[4];
  loadW(0, wcur);
  for (int ks = 0; ks < KC; ks += 32) {
    if (ks + 32 < KC) loadW(ks + 32, wnxt);
    short8_t av0 =
        *reinterpret_cast<const short8_t*>(&As[lm * LDA + ks + lg * 8]);
    short8_t av1 =
        *reinterpret_cast<const short8_t*>(&As[r1c * LDA + ks + lg * 8]);
#pragma unroll
    for (int g = 0; g < 4; ++g) {
      short8_t bv = cvt8(wcur[g]);
      acc[g][0] = __builtin_amdgcn_mfma_f32_16x16x32_bf16(av0, bv, acc[g][0], 0, 0, 0);
      acc[g][1] = __builtin_amdgcn_mfma_f32_16x16x32_bf16(av1, bv, acc[g][1], 0, 0, 0);
    }
    if (ks + 32 < KC) {
#pragma unroll
      for (int g = 0; g < 4; ++g) wcur[g] = wnxt[g];
    }
  }
  float* pp = part + ((long)s * TOK) * N + c0 + lm;
#pragma unroll
  for (int g = 0; g < 4; ++g) {
    float* pg = pp + g * 16;
#pragma unroll
    for (int r = 0; r < 4; ++r) {
      int row0 = lg * 4 + r;
      pg[(long)row0 * N] = acc[g][0][r];
      int row1 = 16 + lg * 4 + r;
      if (row1 < TOK) pg[(long)row1 * N] = acc[g][1][r];
    }
  }
}

// ---------------- patch-embed MFMA GEMM: A gathered from x. W=pe_w[N][K].
template <int KC>
__global__ __launch_bounds__(256) void k_mfma_pe(
    const float* __restrict__ x, const float* __restrict__ W,
    float* __restrict__ part, int K, int N) {
  constexpr int LDA = KC + 8;
  __shared__ __align__(16) unsigned short As[TOK * LDA];
  const int tid = threadIdx.x;
  const int lane = tid & 63;
  const int lm = lane & 15;
  const int lg = lane >> 4;
  const int wv = tid >> 6;
  const int s = blockIdx.y;
  const int k0 = s * KC;
  const int c0 = blockIdx.x * 256 + wv * 64;
  for (int i = tid; i < TOK * (KC / 8); i += 256) {
    int r = i / (KC / 8);
    int o = i - r * (KC / 8);
    int kb = k0 + o * 8;
    int c = kb >> 4;
    int kh0 = (kb >> 2) & 3;
    int py = r / 5, px = r - py * 5;
    const float* xp = x + c * 400 + (py * 4 + kh0) * 20 + px * 4;
    float4 lo = *reinterpret_cast<const float4*>(xp);
    float4 hi = *reinterpret_cast<const float4*>(xp + 20);
    floatx8 f = {lo.x, lo.y, lo.z, lo.w, hi.x, hi.y, hi.z, hi.w};
    *reinterpret_cast<short8_t*>(&As[r * LDA + o * 8]) = cvt8(f);
  }
  __syncthreads();
  const int r1 = 16 + lm;
  const int r1c = (r1 < TOK) ? r1 : 0;
  f32x4_t acc[4][2];
#pragma unroll
  for (int g = 0; g < 4; ++g) {
    acc[g][0] = (f32x4_t){0.f, 0.f, 0.f, 0.f};
    acc[g][1] = (f32x4_t){0.f, 0.f, 0.f, 0.f};
  }
  for (int ks = 0; ks < KC; ks += 32) {
    const int kb = k0 + ks + lg * 8;
    floatx8 bfv[4];
#pragma unroll
    for (int g = 0; g < 4; ++g) {
      const float* bp = W + (long)(c0 + g * 16 + lm) * K + kb;
      float4 b0 = *reinterpret_cast<const float4*>(bp);
      float4 b1 = *reinterpret_cast<const float4*>(bp + 4);
      bfv[g] = (floatx8){b0.x, b0.y, b0.z, b0.w, b1.x, b1.y, b1.z, b1.w};
    }
    short8_t av0 =
        *reinterpret_cast<const short8_t*>(&As[lm * LDA + ks + lg * 8]);
    short8_t av1 =
        *reinterpret_cast<const short8_t*>(&As[r1c * LDA + ks + lg * 8]);
#pragma unroll
    for (int g = 0; g < 4; ++g) {
      short8_t bv = cvt8(bfv[g]);
      acc[g][0] = __builtin_amdgcn_mfma_f32_16x16x32_bf16(av0, bv, acc[g][0], 0, 0, 0);
      acc[g][1] = __builtin_amdgcn_mfma_f32_16x16x32_bf16(av1, bv, acc[g][1], 0, 0, 0);
    }
  }
  float* pp = part + ((long)s * TOK) * N + c0 + lm;
#pragma unroll
  for (int g = 0; g < 4; ++g) {
    float* pg = pp + g * 16;
#pragma unroll
    for (int r = 0; r < 4; ++r) {
      int row0 = lg * 4 + r;
      pg[(long)row0 * N] = acc[g][0][r];
      int row1 = 16 + lg * 4 + r;
      if (row1 < TOK) pg[(long)row1 * N] = acc[g][1][r];
    }
  }
}

// ---------------- reduce partials + bias (+gelu) (+residual) (+LN stats)
// STATS requires Nout==4096 (one block spans a quarter token-row).
template <int S, int GELU, int RES, int OBF, int STATS>
__global__ __launch_bounds__(256) void k_reduce(const float* __restrict__ part,
                                                const float* __restrict__ bias,
                                                const float* __restrict__ res,
                                                void* __restrict__ outv,
                                                float* __restrict__ stats,
                                                int Nout) {
  const int tid = threadIdx.x;
  long idx4 = (long)blockIdx.x * 256 + tid;  // float4 index
  int c4 = (int)(idx4 % (Nout >> 2));
  const long stride4 = (long)TOK * (Nout >> 2);
  const float4* p4 = reinterpret_cast<const float4*>(part) + idx4;
  float4 v = {0.f, 0.f, 0.f, 0.f};
#pragma unroll
  for (int s = 0; s < S; ++s) {
    float4 t = p4[s * stride4];
    v.x += t.x; v.y += t.y; v.z += t.z; v.w += t.w;
  }
  float4 bb = reinterpret_cast<const float4*>(bias)[c4];
  v.x += bb.x; v.y += bb.y; v.z += bb.z; v.w += bb.w;
  if (GELU) {
    v.x = 0.5f * v.x * (1.f + erff(v.x * 0.70710678118654752f));
    v.y = 0.5f * v.y * (1.f + erff(v.y * 0.70710678118654752f));
    v.z = 0.5f * v.z * (1.f + erff(v.z * 0.70710678118654752f));
    v.w = 0.5f * v.w * (1.f + erff(v.w * 0.70710678118654752f));
  }
  if (RES) {
    float4 rr = reinterpret_cast<const float4*>(res)[idx4];
    v.x += rr.x; v.y += rr.y; v.z += rr.z; v.w += rr.w;
  }
  if (OBF) {
    reinterpret_cast<uint2*>(outv)[idx4] = cvt4pack(v);
  } else {
    reinterpret_cast<float4*>(outv)[idx4] = v;
  }
  if (STATS) {
    float s1 = v.x + v.y + v.z + v.w;
    float s2 = v.x * v.x + v.y * v.y + v.z * v.z + v.w * v.w;
#pragma unroll
    for (int off = 32; off >= 1; off >>= 1) {
      s1 += __shfl_down(s1, off);
      s2 += __shfl_down(s2, off);
    }
    __shared__ float red[8];
    if ((tid & 63) == 0) {
      red[tid >> 6] = s1;
      red[4 + (tid >> 6)] = s2;
    }
    __syncthreads();
    if (tid == 0) {
      int row = blockIdx.x >> 2;  // Nout==4096: block = quarter row
      atomicAdd(&stats[row * 2], red[0] + red[1] + red[2] + red[3]);
      atomicAdd(&stats[row * 2 + 1], red[4] + red[5] + red[6] + red[7]);
    }
  }
}

// ---------------- fused attention: QK^T + softmax/64 + PV -> O_bf[25][4096]
__global__ __launch_bounds__(256) void k_attn(const float* __restrict__ qkv,
                                              unsigned short* __restrict__ o) {
  const int head = blockIdx.x;
  __shared__ float q[TOK][260];
  __shared__ float kk[TOK][260];
  __shared__ float att[TOK][TOK];
  const int d = threadIdx.x;
#pragma unroll
  for (int n = 0; n < TOK; ++n) {
    const long base = (long)n * 12288 + (head * 256 + d) * 3;
    q[n][d] = qkv[base];
    kk[n][d] = qkv[base + 1];
  }
  __syncthreads();
  for (int p = threadIdx.x; p < TOK * TOK; p += 256) {
    int i = p / TOK, j = p - i * TOK;
    float acc = 0.f;
#pragma unroll
    for (int c = 0; c < 256; c += 4) {
      float4 a = *reinterpret_cast<const float4*>(&q[i][c]);
      float4 bb = *reinterpret_cast<const float4*>(&kk[j][c]);
      acc = fmaf(a.x, bb.x, acc);
      acc = fmaf(a.y, bb.y, acc);
      acc = fmaf(a.z, bb.z, acc);
      acc = fmaf(a.w, bb.w, acc);
    }
    att[i][j] = acc;
  }
  __syncthreads();
  if (threadIdx.x < TOK) {
    const int i = threadIdx.x;
    float m = -1e30f;
    for (int j = 0; j < TOK; ++j) m = fmaxf(m, att[i][j]);
    float ssum = 0.f;
    float ex[TOK];
#pragma unroll
    for (int j = 0; j < TOK; ++j) {
      ex[j] = expf(att[i][j] - m);
      ssum += ex[j];
    }
    float inv = 1.f / (ssum * 64.f);  // softmax then /sqrt(4096)
#pragma unroll
    for (int j = 0; j < TOK; ++j) att[i][j] = ex[j] * inv;
  }
  __syncthreads();
  float acc[TOK];
#pragma unroll
  for (int i = 0; i < TOK; ++i) acc[i] = 0.f;
#pragma unroll
  for (int j = 0; j < TOK; ++j) {
    float vv = qkv[(long)j * 12288 + (head * 256 + d) * 3 + 2];
#pragma unroll
    for (int i = 0; i < TOK; ++i) acc[i] = fmaf(att[i][j], vv, acc[i]);
  }
#pragma unroll
  for (int i = 0; i < TOK; ++i)
    o[(long)i * 4096 + head * 256 + d] = bf1(acc[i]);
}

extern "C" void kernel_launch(void* const* d_in, const int* in_sizes, int n_in,
                              void* d_out, int out_size, void* d_ws, size_t ws_size,
                              hipStream_t stream) {
  (void)in_sizes; (void)n_in; (void)out_size; (void)ws_size;
  const float* x      = (const float*)d_in[0];
  const float* pe_w   = (const float*)d_in[1];
  const float* pe_b   = (const float*)d_in[2];
  const float* pos    = (const float*)d_in[3];
  const float* ln_g   = (const float*)d_in[4];
  const float* ln_b   = (const float*)d_in[5];
  const float* qkv_w  = (const float*)d_in[6];
  const float* qkv_b  = (const float*)d_in[7];
  const float* proj_w = (const float*)d_in[8];
  const float* proj_b = (const float*)d_in[9];
  const float* ff1_w  = (const float*)d_in[10];
  const float* ff1_b  = (const float*)d_in[11];
  const float* ff2_w  = (const float*)d_in[12];
  const float* ff2_b  = (const float*)d_in[13];
  float* out = (float*)d_out;

  float* ws = (float*)d_ws;
  float* T    = ws + 102400;    // 102400 f32
  float* QKV  = ws + 307200;    // 307200 f32
  unsigned short* O_bf = (unsigned short*)(ws + 614400);      // 102400 bf16
  unsigned short* G_bf = (unsigned short*)(ws + 716800);      // 409600 bf16
  float* STATS0 = ws + 1126400; // 50 f32
  float* STATS1 = ws + 1126464; // 50 f32
  float* PART = ws + 1136400;   // max 16*25*16384 f32 = 26.2 MB

  hipMemsetAsync(STATS0, 0, 128 * sizeof(float), stream);

  // 1. patch embedding (patchify fused into A-stage): KC=128 -> S=32
  k_mfma_pe<128><<<dim3(16, 32), 256, 0, stream>>>(x, pe_w, PART, 4096, 4096);
  k_reduce<32, 0, 1, 0, 1><<<100, 256, 0, stream>>>(PART, pe_b, pos, T, STATS0, 4096);

  // 2. attention branch: qkv KC=256 -> S=16, grid(48,16)=768; LN fused in A-stage
  k_mfma<256, 0, 1><<<dim3(48, 16), 256, 0, stream>>>(T, qkv_w, STATS0, ln_g, ln_b,
                                                      PART, 4096, 12288);
  k_reduce<16, 0, 0, 0, 0><<<300, 256, 0, stream>>>(PART, qkv_b, nullptr, QKV,
                                                    nullptr, 12288);
  k_attn<<<16, 256, 0, stream>>>(QKV, O_bf);
  // proj KC=128 -> S=32, grid(16,32)=512
  k_mfma<128, 0, 0><<<dim3(16, 32), 256, 0, stream>>>(O_bf, proj_w, nullptr, nullptr,
                                                      nullptr, PART, 4096, 4096);
  k_reduce<32, 0, 1, 0, 1><<<100, 256, 0, stream>>>(PART, proj_b, T, T, STATS1, 4096);

  // 3. FFN: ff1 KC=256 -> S=16, grid(64,16)=1024; LN fused; bf16 out
  k_mfma<256, 0, 1><<<dim3(64, 16), 256, 0, stream>>>(T, ff1_w, STATS1, ln_g, ln_b,
                                                      PART, 4096, 16384);
  k_reduce<16, 1, 0, 1, 0><<<400, 256, 0, stream>>>(PART, ff1_b, nullptr, G_bf,
                                                    nullptr, 16384);
  // ff2 KC=512 -> S=32, grid(16,32)=512
  k_mfma<512, 0, 0><<<dim3(16, 32), 256, 0, stream>>>(G_bf, ff2_w, nullptr, nullptr,
                                                      nullptr, PART, 16384, 4096);
  k_reduce<32, 0, 1, 0, 0><<<100, 256, 0, stream>>>(PART, ff2_b, T, out, nullptr, 4096);
}

// Round 10
// 233.986 us; speedup vs baseline: 1.0717x; 1.0717x over previous
//
#include <hip/hip_runtime.h>
#include <math.h>

#define TOK 25

typedef __attribute__((ext_vector_type(8))) short short8_t;   // 8 bf16 (MFMA frag)
typedef __attribute__((ext_vector_type(4))) float f32x4_t;    // MFMA acc
typedef __attribute__((ext_vector_type(8))) float floatx8;
typedef __attribute__((ext_vector_type(4))) float floatx4;
typedef __attribute__((ext_vector_type(8))) __bf16 bf16x8_t;
typedef __attribute__((ext_vector_type(4))) __bf16 bf16x4_t;

// f32x8 -> bf16x8 via v_cvt_pk_bf16_f32 (compiler-lowered), as MFMA short8 frag
__device__ __forceinline__ short8_t cvt8(floatx8 f) {
  return __builtin_bit_cast(short8_t, __builtin_convertvector(f, bf16x8_t));
}
__device__ __forceinline__ uint2 cvt4pack(float4 v) {
  floatx4 f = {v.x, v.y, v.z, v.w};
  return __builtin_bit_cast(uint2, __builtin_convertvector(f, bf16x4_t));
}
__device__ __forceinline__ uint2 pack4(f32x4_t v) {
  floatx4 f = {v[0], v[1], v[2], v[3]};
  return __builtin_bit_cast(uint2, __builtin_convertvector(f, bf16x4_t));
}
__device__ __forceinline__ unsigned short bf1(float f) {
  return __builtin_bit_cast(unsigned short, (__bf16)f);
}

// Partial layout: uint2 part[s][N/16][2(half)][64(lane)]
//   lane = lg*16+lm ; uint2 = 4 bf16 rows {half*16+lg*4+0..3} of col ct*16+lm.
// GEMM stores are 512B-contiguous per wave instruction; reduce reads coalesced.

// ---------------- MFMA GEMM: A_bf[25][K] * W -> packed bf16 partials
// Block: 4 waves, 256 cols; wave owns 64 cols (4 groups of 16).
// A staged in LDS as bf16. One-step register double-buffer on the W stream.
// WT=0: W[K][N].  WT=1: W[N][K].
template <int KC, int WT>
__global__ __launch_bounds__(256) void k_mfma(
    const unsigned short* __restrict__ A, const float* __restrict__ W,
    uint2* __restrict__ part, int K, int N) {
  constexpr int LDA = KC + 8;  // bf16 elems/row; +16B pad
  __shared__ __align__(16) unsigned short As[TOK * LDA];
  const int tid = threadIdx.x;
  const int lane = tid & 63;
  const int lm = lane & 15;   // A row / B col within 16
  const int lg = lane >> 4;   // k-group (8 elems)
  const int wv = tid >> 6;
  const int s = blockIdx.y;
  const int k0 = s * KC;
  const int c0 = blockIdx.x * 256 + wv * 64;  // wave's first col
  // ---- stage A tile: 25 x KC bf16
  for (int i = tid; i < TOK * (KC / 8); i += 256) {
    int r = i / (KC / 8);
    int o = i - r * (KC / 8);
    uint4 v = *reinterpret_cast<const uint4*>(A + (long)r * K + k0 + o * 8);
    *reinterpret_cast<uint4*>(&As[r * LDA + o * 8]) = v;
  }
  __syncthreads();
  const int r1 = 16 + lm;
  const int r1c = (r1 < TOK) ? r1 : 0;  // clamped; rows >=25 dropped in reduce
  f32x4_t acc[4][2];
#pragma unroll
  for (int g = 0; g < 4; ++g) {
    acc[g][0] = (f32x4_t){0.f, 0.f, 0.f, 0.f};
    acc[g][1] = (f32x4_t){0.f, 0.f, 0.f, 0.f};
  }
  auto loadW = [&](int ks, floatx8(&dst)[4]) {
    const int kb = k0 + ks + lg * 8;
    if (WT == 0) {
      const float* bp = W + (long)kb * N + c0 + lm;
#pragma unroll
      for (int j = 0; j < 8; ++j) {
        const float* bj = bp + (long)j * N;
#pragma unroll
        for (int g = 0; g < 4; ++g) dst[g][j] = bj[g * 16];
      }
    } else {
#pragma unroll
      for (int g = 0; g < 4; ++g) {
        const float* bp = W + (long)(c0 + g * 16 + lm) * K + kb;
        float4 b0 = *reinterpret_cast<const float4*>(bp);
        float4 b1 = *reinterpret_cast<const float4*>(bp + 4);
        dst[g] = (floatx8){b0.x, b0.y, b0.z, b0.w, b1.x, b1.y, b1.z, b1.w};
      }
    }
  };
  floatx8 wcur[4], wnxt[4];
  loadW(0, wcur);
  for (int ks = 0; ks < KC; ks += 32) {
    if (ks + 32 < KC) loadW(ks + 32, wnxt);
    short8_t av0 =
        *reinterpret_cast<const short8_t*>(&As[lm * LDA + ks + lg * 8]);
    short8_t av1 =
        *reinterpret_cast<const short8_t*>(&As[r1c * LDA + ks + lg * 8]);
#pragma unroll
    for (int g = 0; g < 4; ++g) {
      short8_t bv = cvt8(wcur[g]);
      acc[g][0] = __builtin_amdgcn_mfma_f32_16x16x32_bf16(av0, bv, acc[g][0], 0, 0, 0);
      acc[g][1] = __builtin_amdgcn_mfma_f32_16x16x32_bf16(av1, bv, acc[g][1], 0, 0, 0);
    }
    if (ks + 32 < KC) {
#pragma unroll
      for (int g = 0; g < 4; ++g) wcur[g] = wnxt[g];
    }
  }
  // ---- packed store: 512B contiguous per (g, half)
  const long sbase = (long)s * N * 8;  // uint2 per slice = N/16*2*64 = N*8
#pragma unroll
  for (int g = 0; g < 4; ++g) {
    long t = ((long)(c0 >> 4) + g) * 128;
    part[sbase + t + lane] = pack4(acc[g][0]);
    part[sbase + t + 64 + lane] = pack4(acc[g][1]);
  }
}

// ---------------- patch-embed MFMA GEMM: A gathered from x. W=pe_w[N][K].
template <int KC>
__global__ __launch_bounds__(256) void k_mfma_pe(
    const float* __restrict__ x, const float* __restrict__ W,
    uint2* __restrict__ part, int K, int N) {
  constexpr int LDA = KC + 8;
  __shared__ __align__(16) unsigned short As[TOK * LDA];
  const int tid = threadIdx.x;
  const int lane = tid & 63;
  const int lm = lane & 15;
  const int lg = lane >> 4;
  const int wv = tid >> 6;
  const int s = blockIdx.y;
  const int k0 = s * KC;
  const int c0 = blockIdx.x * 256 + wv * 64;
  for (int i = tid; i < TOK * (KC / 8); i += 256) {
    int r = i / (KC / 8);
    int o = i - r * (KC / 8);
    int kb = k0 + o * 8;
    int c = kb >> 4;
    int kh0 = (kb >> 2) & 3;
    int py = r / 5, px = r - py * 5;
    const float* xp = x + c * 400 + (py * 4 + kh0) * 20 + px * 4;
    float4 lo = *reinterpret_cast<const float4*>(xp);
    float4 hi = *reinterpret_cast<const float4*>(xp + 20);
    floatx8 f = {lo.x, lo.y, lo.z, lo.w, hi.x, hi.y, hi.z, hi.w};
    *reinterpret_cast<short8_t*>(&As[r * LDA + o * 8]) = cvt8(f);
  }
  __syncthreads();
  const int r1 = 16 + lm;
  const int r1c = (r1 < TOK) ? r1 : 0;
  f32x4_t acc[4][2];
#pragma unroll
  for (int g = 0; g < 4; ++g) {
    acc[g][0] = (f32x4_t){0.f, 0.f, 0.f, 0.f};
    acc[g][1] = (f32x4_t){0.f, 0.f, 0.f, 0.f};
  }
  for (int ks = 0; ks < KC; ks += 32) {
    const int kb = k0 + ks + lg * 8;
    floatx8 bfv[4];
#pragma unroll
    for (int g = 0; g < 4; ++g) {
      const float* bp = W + (long)(c0 + g * 16 + lm) * K + kb;
      float4 b0 = *reinterpret_cast<const float4*>(bp);
      float4 b1 = *reinterpret_cast<const float4*>(bp + 4);
      bfv[g] = (floatx8){b0.x, b0.y, b0.z, b0.w, b1.x, b1.y, b1.z, b1.w};
    }
    short8_t av0 =
        *reinterpret_cast<const short8_t*>(&As[lm * LDA + ks + lg * 8]);
    short8_t av1 =
        *reinterpret_cast<const short8_t*>(&As[r1c * LDA + ks + lg * 8]);
#pragma unroll
    for (int g = 0; g < 4; ++g) {
      short8_t bv = cvt8(bfv[g]);
      acc[g][0] = __builtin_amdgcn_mfma_f32_16x16x32_bf16(av0, bv, acc[g][0], 0, 0, 0);
      acc[g][1] = __builtin_amdgcn_mfma_f32_16x16x32_bf16(av1, bv, acc[g][1], 0, 0, 0);
    }
  }
  const long sbase = (long)s * N * 8;
#pragma unroll
  for (int g = 0; g < 4; ++g) {
    long t = ((long)(c0 >> 4) + g) * 128;
    part[sbase + t + lane] = pack4(acc[g][0]);
    part[sbase + t + 64 + lane] = pack4(acc[g][1]);
  }
}

// ---------------- reduce packed partials + bias (+gelu) (+residual)
// grid = Nout*8/256 blocks; thread owns 4 rows x 1 col.
template <int S, int GELU, int RES, int OBF>
__global__ __launch_bounds__(256) void k_reduce(const uint2* __restrict__ part,
                                                const float* __restrict__ bias,
                                                const float* __restrict__ res,
                                                void* __restrict__ outv,
                                                int Nout) {
  const long gidx = (long)blockIdx.x * 256 + threadIdx.x;
  const int lane = (int)(gidx & 63);
  const int half = (int)((gidx >> 6) & 1);
  const long ct = gidx >> 7;
  const int lm = lane & 15, lg = lane >> 4;
  const int col = (int)(ct * 16 + lm);
  const long stride = (long)Nout * 8;  // uint2 per s-slice
  const uint2* pp = part + gidx;
  float a[4] = {0.f, 0.f, 0.f, 0.f};
#pragma unroll
  for (int s = 0; s < S; ++s) {
    uint2 u = pp[(long)s * stride];
    a[0] += __builtin_bit_cast(float, (u.x & 0xffffu) << 16);
    a[1] += __builtin_bit_cast(float, u.x & 0xffff0000u);
    a[2] += __builtin_bit_cast(float, (u.y & 0xffffu) << 16);
    a[3] += __builtin_bit_cast(float, u.y & 0xffff0000u);
  }
  const float bb = bias[col];
#pragma unroll
  for (int r = 0; r < 4; ++r) {
    a[r] += bb;
    if (GELU) a[r] = 0.5f * a[r] * (1.f + erff(a[r] * 0.70710678118654752f));
  }
  const int row0 = half * 16 + lg * 4;
#pragma unroll
  for (int r = 0; r < 4; ++r) {
    int row = row0 + r;
    if (row < TOK) {
      float v = a[r];
      if (RES) v += res[(long)row * Nout + col];
      if (OBF) {
        ((unsigned short*)outv)[(long)row * Nout + col] = bf1(v);
      } else {
        ((float*)outv)[(long)row * Nout + col] = v;
      }
    }
  }
}

// ---------------- LayerNorm over 4096, one block per token -> bf16 out
__global__ __launch_bounds__(256) void k_ln(const float* __restrict__ t,
                                            const float* __restrict__ g,
                                            const float* __restrict__ b,
                                            unsigned short* __restrict__ h) {
  const int n = blockIdx.x;
  const float4* row = reinterpret_cast<const float4*>(t + n * 4096);
  float s = 0.f, s2 = 0.f;
  float4 vbuf[4];
#pragma unroll
  for (int it = 0; it < 4; ++it) {
    float4 v = row[threadIdx.x + it * 256];
    vbuf[it] = v;
    s += v.x + v.y + v.z + v.w;
    s2 += v.x * v.x + v.y * v.y + v.z * v.z + v.w * v.w;
  }
#pragma unroll
  for (int off = 32; off >= 1; off >>= 1) {
    s += __shfl_down(s, off);
    s2 += __shfl_down(s2, off);
  }
  __shared__ float red[8];
  if ((threadIdx.x & 63) == 0) {
    red[threadIdx.x >> 6] = s;
    red[4 + (threadIdx.x >> 6)] = s2;
  }
  __syncthreads();
  float st = red[0] + red[1] + red[2] + red[3];
  float s2t = red[4] + red[5] + red[6] + red[7];
  float mean = st * (1.f / 4096.f);
  float var = s2t * (1.f / 4096.f) - mean * mean;
  float rstd = rsqrtf(var + 1e-5f);
  const float4* g4 = reinterpret_cast<const float4*>(g);
  const float4* b4 = reinterpret_cast<const float4*>(b);
  uint2* h2 = reinterpret_cast<uint2*>(h) + (long)n * 1024;
#pragma unroll
  for (int it = 0; it < 4; ++it) {
    int i = threadIdx.x + it * 256;
    float4 v = vbuf[it];
    float4 gg = g4[i];
    float4 bb = b4[i];
    float4 o;
    o.x = (v.x - mean) * rstd * gg.x + bb.x;
    o.y = (v.y - mean) * rstd * gg.y + bb.y;
    o.z = (v.z - mean) * rstd * gg.z + bb.z;
    o.w = (v.w - mean) * rstd * gg.w + bb.w;
    h2[i] = cvt4pack(o);
  }
}

// ---------------- fused attention: QK^T + softmax/64 + PV -> O_bf[25][4096]
__global__ __launch_bounds__(256) void k_attn(const float* __restrict__ qkv,
                                              unsigned short* __restrict__ o) {
  const int head = blockIdx.x;
  __shared__ float q[TOK][260];
  __shared__ float kk[TOK][260];
  __shared__ float att[TOK][TOK];
  const int d = threadIdx.x;
#pragma unroll
  for (int n = 0; n < TOK; ++n) {
    const long base = (long)n * 12288 + (head * 256 + d) * 3;
    q[n][d] = qkv[base];
    kk[n][d] = qkv[base + 1];
  }
  __syncthreads();
  for (int p = threadIdx.x; p < TOK * TOK; p += 256) {
    int i = p / TOK, j = p - i * TOK;
    float acc = 0.f;
#pragma unroll
    for (int c = 0; c < 256; c += 4) {
      float4 a = *reinterpret_cast<const float4*>(&q[i][c]);
      float4 bb = *reinterpret_cast<const float4*>(&kk[j][c]);
      acc = fmaf(a.x, bb.x, acc);
      acc = fmaf(a.y, bb.y, acc);
      acc = fmaf(a.z, bb.z, acc);
      acc = fmaf(a.w, bb.w, acc);
    }
    att[i][j] = acc;
  }
  __syncthreads();
  if (threadIdx.x < TOK) {
    const int i = threadIdx.x;
    float m = -1e30f;
    for (int j = 0; j < TOK; ++j) m = fmaxf(m, att[i][j]);
    float ssum = 0.f;
    float ex[TOK];
#pragma unroll
    for (int j = 0; j < TOK; ++j) {
      ex[j] = expf(att[i][j] - m);
      ssum += ex[j];
    }
    float inv = 1.f / (ssum * 64.f);  // softmax then /sqrt(4096)
#pragma unroll
    for (int j = 0; j < TOK; ++j) att[i][j] = ex[j] * inv;
  }
  __syncthreads();
  float acc[TOK];
#pragma unroll
  for (int i = 0; i < TOK; ++i) acc[i] = 0.f;
#pragma unroll
  for (int j = 0; j < TOK; ++j) {
    float vv = qkv[(long)j * 12288 + (head * 256 + d) * 3 + 2];
#pragma unroll
    for (int i = 0; i < TOK; ++i) acc[i] = fmaf(att[i][j], vv, acc[i]);
  }
#pragma unroll
  for (int i = 0; i < TOK; ++i)
    o[(long)i * 4096 + head * 256 + d] = bf1(acc[i]);
}

extern "C" void kernel_launch(void* const* d_in, const int* in_sizes, int n_in,
                              void* d_out, int out_size, void* d_ws, size_t ws_size,
                              hipStream_t stream) {
  (void)in_sizes; (void)n_in; (void)out_size; (void)ws_size;
  const float* x      = (const float*)d_in[0];
  const float* pe_w   = (const float*)d_in[1];
  const float* pe_b   = (const float*)d_in[2];
  const float* pos    = (const float*)d_in[3];
  const float* ln_g   = (const float*)d_in[4];
  const float* ln_b   = (const float*)d_in[5];
  const float* qkv_w  = (const float*)d_in[6];
  const float* qkv_b  = (const float*)d_in[7];
  const float* proj_w = (const float*)d_in[8];
  const float* proj_b = (const float*)d_in[9];
  const float* ff1_w  = (const float*)d_in[10];
  const float* ff1_b  = (const float*)d_in[11];
  const float* ff2_w  = (const float*)d_in[12];
  const float* ff2_b  = (const float*)d_in[13];
  float* out = (float*)d_out;

  float* ws = (float*)d_ws;
  float* T    = ws + 102400;    // 102400 f32
  unsigned short* H_bf = (unsigned short*)(ws + 204800);      // 102400 bf16
  float* QKV  = ws + 307200;    // 307200 f32
  unsigned short* O_bf = (unsigned short*)(ws + 614400);      // 102400 bf16
  unsigned short* G_bf = (unsigned short*)(ws + 716800);      // 409600 bf16
  uint2* PART = (uint2*)(ws + 1136400);  // max 16.8 MB (ff1)

  // 1. patch embedding (patchify fused into A-stage): KC=128 -> S=32
  k_mfma_pe<128><<<dim3(16, 32), 256, 0, stream>>>(x, pe_w, PART, 4096, 4096);
  k_reduce<32, 0, 1, 0><<<128, 256, 0, stream>>>(PART, pe_b, pos, T, 4096);
  k_ln<<<25, 256, 0, stream>>>(T, ln_g, ln_b, H_bf);

  // 2. attention branch: qkv KC=256 -> S=16, grid(48,16)=768
  k_mfma<256, 0><<<dim3(48, 16), 256, 0, stream>>>(H_bf, qkv_w, PART, 4096, 12288);
  k_reduce<16, 0, 0, 0><<<384, 256, 0, stream>>>(PART, qkv_b, nullptr, QKV, 12288);
  k_attn<<<16, 256, 0, stream>>>(QKV, O_bf);
  // proj KC=128 -> S=32, grid(16,32)=512
  k_mfma<128, 0><<<dim3(16, 32), 256, 0, stream>>>(O_bf, proj_w, PART, 4096, 4096);
  k_reduce<32, 0, 1, 0><<<128, 256, 0, stream>>>(PART, proj_b, T, T, 4096);
  k_ln<<<25, 256, 0, stream>>>(T, ln_g, ln_b, H_bf);

  // 3. FFN: ff1 KC=256 -> S=16, grid(64,16)=1024; bf16 out
  k_mfma<256, 0><<<dim3(64, 16), 256, 0, stream>>>(H_bf, ff1_w, PART, 4096, 16384);
  k_reduce<16, 1, 0, 1><<<512, 256, 0, stream>>>(PART, ff1_b, nullptr, G_bf, 16384);
  // ff2 KC=512 -> S=32, grid(16,32)=512
  k_mfma<512, 0><<<dim3(16, 32), 256, 0, stream>>>(G_bf, ff2_w, PART, 16384, 4096);
  k_reduce<32, 0, 1, 0><<<128, 256, 0, stream>>>(PART, ff2_b, T, out, 4096);
}